// Round 1
// baseline (3882.457 us; speedup 1.0000x reference)
//
#include <hip/hip_runtime.h>
#include <math.h>

#define T_LEN 2048
#define E_DIM 2048
#define H_NUM 16
#define D_DIM 64
#define D2    128
#define CONV_R 64

// 0.8 - 0.6*exp(-3.6)
#define LAMBDA_INIT_F 0.7836057665316245f
#define ONE_MINUS_LI  0.2163942334683755f

#define MODE_PLAIN 0
#define MODE_QK    1
#define MODE_V     2

// ---------------------------------------------------------------------------
// lambda_full = exp(sum lq1*lk1) - exp(sum lq2*lk2) + LAMBDA_INIT
__global__ __launch_bounds__(64) void lambda_kernel(
    const float* __restrict__ lq1, const float* __restrict__ lk1,
    const float* __restrict__ lq2, const float* __restrict__ lk2,
    float* __restrict__ lam)
{
    int l = threadIdx.x;
    float p1 = lq1[l] * lk1[l];
    float p2 = lq2[l] * lk2[l];
    for (int off = 32; off; off >>= 1) {
        p1 += __shfl_down(p1, off, 64);
        p2 += __shfl_down(p2, off, 64);
    }
    if (l == 0) lam[0] = expf(p1) - expf(p2) + LAMBDA_INIT_F;
}

// ---------------------------------------------------------------------------
// g[tau] = (1/T) * sum_k w_k * filt_k * cos(2*pi*k*tau/T),  exact irfft of filt
__global__ __launch_bounds__(64) void gfilt_kernel(float* __restrict__ g)
{
    int tau = blockIdx.x * 64 + threadIdx.x;
    double acc = 0.0;
    for (int k = 0; k <= 1024; ++k) {
        double w = (k == 0 || k == 1024) ? 1.0 : 2.0;
        double xk = (double)k * (1.0 / 1024.0);
        double r = xk * (1.0 / 0.15);
        double f = exp(-0.5 * r * r);
        int m = (k * tau) & 2047;                 // exact phase mod
        double ang = (double)m * (6.283185307179586476925287 / 2048.0);
        acc += w * f * cos(ang);
    }
    g[tau] = (float)(acc * (1.0 / 2048.0));
}

// ---------------------------------------------------------------------------
// Generic fp32 tiled GEMM C(2048x2048) = A(2048x2048) * B(2048x2048)
// mode PLAIN: write Cplain[t*E + c]
// mode QK:    rotary + split even/odd heads into out1/out2 [(h*T + t)*64 + d]
// mode V:     split pairs into out1/out2 [(h*T + t)*64 + d]
__global__ __launch_bounds__(256) void gemm_tile(
    const float* __restrict__ A, const float* __restrict__ B,
    float* __restrict__ Cplain, float* __restrict__ out1, float* __restrict__ out2,
    int mode)
{
    __shared__ float As[64][17];
    __shared__ float Bs[16][65];
    const int tid = threadIdx.x;
    const int tx = tid & 15, ty = tid >> 4;
    const int rb = blockIdx.y * 64, cb = blockIdx.x * 64;

    float acc[4][4] = {};

    for (int k0 = 0; k0 < E_DIM; k0 += 16) {
        // A tile: 64 rows x 16 k
        {
            int row = tid >> 2, kk = (tid & 3) * 4;
            float4 v = *(const float4*)(A + (size_t)(rb + row) * E_DIM + k0 + kk);
            As[row][kk + 0] = v.x; As[row][kk + 1] = v.y;
            As[row][kk + 2] = v.z; As[row][kk + 3] = v.w;
        }
        // B tile: 16 rows x 64 cols
        {
            int brow = tid >> 4, bcol = (tid & 15) * 4;
            float4 v = *(const float4*)(B + (size_t)(k0 + brow) * E_DIM + cb + bcol);
            Bs[brow][bcol + 0] = v.x; Bs[brow][bcol + 1] = v.y;
            Bs[brow][bcol + 2] = v.z; Bs[brow][bcol + 3] = v.w;
        }
        __syncthreads();
        #pragma unroll
        for (int kk = 0; kk < 16; ++kk) {
            float a0 = As[ty * 4 + 0][kk];
            float a1 = As[ty * 4 + 1][kk];
            float a2 = As[ty * 4 + 2][kk];
            float a3 = As[ty * 4 + 3][kk];
            float b0 = Bs[kk][tx * 4 + 0];
            float b1 = Bs[kk][tx * 4 + 1];
            float b2 = Bs[kk][tx * 4 + 2];
            float b3 = Bs[kk][tx * 4 + 3];
            acc[0][0] += a0 * b0; acc[0][1] += a0 * b1; acc[0][2] += a0 * b2; acc[0][3] += a0 * b3;
            acc[1][0] += a1 * b0; acc[1][1] += a1 * b1; acc[1][2] += a1 * b2; acc[1][3] += a1 * b3;
            acc[2][0] += a2 * b0; acc[2][1] += a2 * b1; acc[2][2] += a2 * b2; acc[2][3] += a2 * b3;
            acc[3][0] += a3 * b0; acc[3][1] += a3 * b1; acc[3][2] += a3 * b2; acc[3][3] += a3 * b3;
        }
        __syncthreads();
    }

    if (mode == MODE_PLAIN) {
        #pragma unroll
        for (int i = 0; i < 4; ++i) {
            int t = rb + ty * 4 + i;
            int c = cb + tx * 4;
            float4 v = make_float4(acc[i][0], acc[i][1], acc[i][2], acc[i][3]);
            *(float4*)(Cplain + (size_t)t * E_DIM + c) = v;
        }
    } else if (mode == MODE_QK) {
        #pragma unroll
        for (int i = 0; i < 4; ++i) {
            int t = rb + ty * 4 + i;
            #pragma unroll
            for (int jp = 0; jp < 2; ++jp) {
                int c = cb + tx * 4 + jp * 2;
                int head2 = c >> 6;
                int d = c & 63;
                int fi = d >> 1;
                // inv_freq = 10000^(-fi/32), computed in double
                double inv = exp(-(double)fi * 0.28782313662425575); // ln(1e4)/32
                double ang = (double)t * inv;
                double cs = cos(ang), sn = sin(ang);
                double x1 = (double)acc[i][jp * 2 + 0];
                double x2 = (double)acc[i][jp * 2 + 1];
                float o1 = (float)(x1 * cs - x2 * sn);
                float o2 = (float)(x1 * sn + x2 * cs);
                int h = head2 >> 1, pr = head2 & 1;
                float* dst = (pr ? out2 : out1) + ((size_t)(h * T_LEN + t)) * D_DIM + d;
                dst[0] = o1; dst[1] = o2;
            }
        }
    } else { // MODE_V
        #pragma unroll
        for (int i = 0; i < 4; ++i) {
            int t = rb + ty * 4 + i;
            #pragma unroll
            for (int j = 0; j < 4; ++j) {
                int c = cb + tx * 4 + j;
                int h = c >> 7;
                int r2 = (c >> 6) & 1;
                int d = c & 63;
                float* dst = (r2 ? out2 : out1) + ((size_t)(h * T_LEN + t)) * D_DIM + d;
                dst[0] = acc[i][j];
            }
        }
    }
}

// ---------------------------------------------------------------------------
// Flash-style causal attention for one pair. Writes (or combines into) X[t][h*128+c].
// Q,K,V1,V2: [(h*T + t)*64 + d].  combine=0: X = o ; combine=1: X = X - lam*o
__global__ __launch_bounds__(256) void attn_kernel(
    const float* __restrict__ Q, const float* __restrict__ K,
    const float* __restrict__ V1, const float* __restrict__ V2,
    float* __restrict__ X, const float* __restrict__ lam_ptr, int combine)
{
    const int qt = blockIdx.x;   // q tile (64 rows)
    const int h  = blockIdx.y;
    const int tid = threadIdx.x;
    const int qr = tid & 63;     // q row within tile
    const int kg = tid >> 6;     // column group (0..3)

    __shared__ float Qt[64][65];
    __shared__ float Kt[64][65];
    __shared__ float Vt1[64][65];
    __shared__ float Vt2[64][65];
    __shared__ float Ps[64][65];
    __shared__ float redm[4][64];
    __shared__ float reds[4][64];

    // load Q tile (each thread: one row quarter = 16 floats)
    {
        int row = tid >> 2, c0 = (tid & 3) * 16;
        const float* src = Q + ((size_t)(h * T_LEN) + qt * 64 + row) * D_DIM + c0;
        #pragma unroll
        for (int u = 0; u < 4; ++u) {
            float4 v = *(const float4*)(src + u * 4);
            Qt[row][c0 + u * 4 + 0] = v.x; Qt[row][c0 + u * 4 + 1] = v.y;
            Qt[row][c0 + u * 4 + 2] = v.z; Qt[row][c0 + u * 4 + 3] = v.w;
        }
    }

    float o[32];
    #pragma unroll
    for (int j = 0; j < 32; ++j) o[j] = 0.f;
    float m_loc = -1e30f, l_loc = 0.f;

    const int t_g = qt * 64 + qr;
    const float scale = 0.125f;  // D^-0.5

    for (int kt = 0; kt <= qt; ++kt) {
        __syncthreads(); // protect LDS from previous iteration's readers
        // load K/V tiles
        {
            int row = tid >> 2, c0 = (tid & 3) * 16;
            size_t base = ((size_t)(h * T_LEN) + kt * 64 + row) * D_DIM + c0;
            #pragma unroll
            for (int u = 0; u < 4; ++u) {
                float4 v = *(const float4*)(K + base + u * 4);
                Kt[row][c0 + u * 4 + 0] = v.x; Kt[row][c0 + u * 4 + 1] = v.y;
                Kt[row][c0 + u * 4 + 2] = v.z; Kt[row][c0 + u * 4 + 3] = v.w;
            }
            #pragma unroll
            for (int u = 0; u < 4; ++u) {
                float4 v = *(const float4*)(V1 + base + u * 4);
                Vt1[row][c0 + u * 4 + 0] = v.x; Vt1[row][c0 + u * 4 + 1] = v.y;
                Vt1[row][c0 + u * 4 + 2] = v.z; Vt1[row][c0 + u * 4 + 3] = v.w;
            }
            #pragma unroll
            for (int u = 0; u < 4; ++u) {
                float4 v = *(const float4*)(V2 + base + u * 4);
                Vt2[row][c0 + u * 4 + 0] = v.x; Vt2[row][c0 + u * 4 + 1] = v.y;
                Vt2[row][c0 + u * 4 + 2] = v.z; Vt2[row][c0 + u * 4 + 3] = v.w;
            }
        }
        __syncthreads();

        // S tile: this thread computes cols kc = kg*16 + [0,16)
        float sv[16];
        #pragma unroll
        for (int j = 0; j < 16; ++j) sv[j] = 0.f;
        for (int d = 0; d < 64; ++d) {
            float qd = Qt[qr][d];
            #pragma unroll
            for (int j = 0; j < 16; ++j) sv[j] += qd * Kt[kg * 16 + j][d];
        }
        float pm = -1e30f;
        #pragma unroll
        for (int j = 0; j < 16; ++j) {
            int s_g = kt * 64 + kg * 16 + j;
            sv[j] = (s_g <= t_g) ? sv[j] * scale : -1e30f;
            pm = fmaxf(pm, sv[j]);
        }
        redm[kg][qr] = pm;
        __syncthreads();

        float tilemax = fmaxf(fmaxf(redm[0][qr], redm[1][qr]),
                              fmaxf(redm[2][qr], redm[3][qr]));
        float m_old = m_loc;
        float newm = fmaxf(m_old, tilemax);
        float alpha = expf(m_old - newm);
        float ps = 0.f;
        #pragma unroll
        for (int j = 0; j < 16; ++j) {
            float p = expf(sv[j] - newm);
            Ps[qr][kg * 16 + j] = p;
            ps += p;
        }
        reds[kg][qr] = ps;
        __syncthreads();

        float tilesum = reds[0][qr] + reds[1][qr] + reds[2][qr] + reds[3][qr];
        l_loc = l_loc * alpha + tilesum;
        m_loc = newm;

        // PV: this thread owns output cols kg*32 + [0,32)
        const float (*Vt)[65] = (kg < 2) ? (const float (*)[65])Vt1
                                         : (const float (*)[65])Vt2;
        const int cbv = (kg & 1) * 32;
        #pragma unroll
        for (int j = 0; j < 32; ++j) o[j] *= alpha;
        for (int kc = 0; kc < 64; ++kc) {
            float pp = Ps[qr][kc];
            #pragma unroll
            for (int j = 0; j < 32; ++j) o[j] += pp * Vt[kc][cbv + j];
        }
    }

    // epilogue
    float rinv = 1.f / l_loc;
    size_t base = (size_t)t_g * E_DIM + h * D2 + kg * 32;
    if (!combine) {
        #pragma unroll
        for (int j = 0; j < 32; ++j) X[base + j] = o[j] * rinv;
    } else {
        float lam = lam_ptr[0];
        #pragma unroll
        for (int j = 0; j < 32; ++j) X[base + j] = X[base + j] - lam * (o[j] * rinv);
    }
}

// ---------------------------------------------------------------------------
// Truncated circular convolution along t: Y[t][c] = sum_{tau=-R..R} g[tau mod T] * X[(t-tau) mod T][c]
__global__ __launch_bounds__(256) void conv_kernel(
    const float* __restrict__ X, const float* __restrict__ g, float* __restrict__ Y)
{
    int c = blockIdx.x * 256 + threadIdx.x;
    int t = blockIdx.y;
    float acc = 0.f;
    #pragma unroll 4
    for (int tau = -CONV_R; tau <= CONV_R; ++tau) {
        int gi = (tau + T_LEN) & (T_LEN - 1);
        int s  = (t - tau + T_LEN) & (T_LEN - 1);
        acc += g[gi] * X[(size_t)s * E_DIM + c];
    }
    Y[(size_t)t * E_DIM + c] = acc;
}

// ---------------------------------------------------------------------------
// RMSNorm over last 128 dims per (t,h), in place, * rms_weight * (1-LAMBDA_INIT)
__global__ __launch_bounds__(64) void rms_kernel(
    float* __restrict__ Y, const float* __restrict__ w)
{
    int grp = blockIdx.x;         // t*16 + h
    int t = grp >> 4, h = grp & 15;
    int l = threadIdx.x;
    size_t base = (size_t)t * E_DIM + h * D2;
    float a = Y[base + l];
    float b = Y[base + 64 + l];
    float ss = a * a + b * b;
    for (int off = 32; off; off >>= 1) ss += __shfl_down(ss, off, 64);
    ss = __shfl(ss, 0, 64);
    float r = rsqrtf(ss * (1.f / 128.f) + 1e-5f) * ONE_MINUS_LI;
    Y[base + l]      = a * r * w[l];
    Y[base + 64 + l] = b * r * w[64 + l];
}

// ---------------------------------------------------------------------------
extern "C" void kernel_launch(void* const* d_in, const int* in_sizes, int n_in,
                              void* d_out, int out_size, void* d_ws, size_t ws_size,
                              hipStream_t stream)
{
    const float* query = (const float*)d_in[0];
    const float* Wq    = (const float*)d_in[1];
    const float* Wk    = (const float*)d_in[2];
    const float* Wv    = (const float*)d_in[3];
    const float* Wout  = (const float*)d_in[4];
    const float* lq1   = (const float*)d_in[5];
    const float* lk1   = (const float*)d_in[6];
    const float* lq2   = (const float*)d_in[7];
    const float* lk2   = (const float*)d_in[8];
    const float* rmsw  = (const float*)d_in[9];
    float* out = (float*)d_out;

    const size_t HTD = (size_t)H_NUM * T_LEN * D_DIM;  // 2,097,152
    const size_t TE  = (size_t)T_LEN * E_DIM;          // 4,194,304
    float* ws = (float*)d_ws;
    float* q1 = ws;
    float* q2 = q1 + HTD;
    float* k1 = q2 + HTD;
    float* k2 = k1 + HTD;
    float* v1 = k2 + HTD;
    float* v2 = v1 + HTD;
    float* x  = v2 + HTD;      // attn1, then attn1 - lam*attn2
    float* y  = x + TE;        // conv out, then rms'd in place
    float* g  = y + TE;        // 2048
    float* lam = g + T_LEN;    // 1

    lambda_kernel<<<1, 64, 0, stream>>>(lq1, lk1, lq2, lk2, lam);
    gfilt_kernel<<<32, 64, 0, stream>>>(g);

    dim3 ggrid(E_DIM / 64, T_LEN / 64);
    gemm_tile<<<ggrid, 256, 0, stream>>>(query, Wq, nullptr, q1, q2, MODE_QK);
    gemm_tile<<<ggrid, 256, 0, stream>>>(query, Wk, nullptr, k1, k2, MODE_QK);
    gemm_tile<<<ggrid, 256, 0, stream>>>(query, Wv, nullptr, v1, v2, MODE_V);

    dim3 agrid(T_LEN / 64, H_NUM);
    attn_kernel<<<agrid, 256, 0, stream>>>(q1, k1, v1, v2, x, lam, 0);
    attn_kernel<<<agrid, 256, 0, stream>>>(q2, k2, v1, v2, x, lam, 1);

    dim3 cgrid(E_DIM / 256, T_LEN);
    conv_kernel<<<cgrid, 256, 0, stream>>>(x, g, y);

    rms_kernel<<<T_LEN * H_NUM, 64, 0, stream>>>(y, rmsw);

    gemm_tile<<<ggrid, 256, 0, stream>>>(y, Wout, out, nullptr, nullptr, MODE_PLAIN);
}

// Round 2
// 726.328 us; speedup vs baseline: 5.3453x; 5.3453x over previous
//
#include <hip/hip_runtime.h>
#include <math.h>

#define MODE_PLAIN 0
#define MODE_QK    1
#define MODE_V     2

#define LAMBDA_INIT_F 0.7836057665316245f
#define ONE_MINUS_LI  0.2163942334683755f

typedef unsigned short ushort_t;
typedef unsigned int   uint32;
typedef unsigned long long u64;
typedef __attribute__((ext_vector_type(8))) short short8;
typedef __attribute__((ext_vector_type(4))) float f32x4;

// float -> bf16 (RNE)
__device__ __forceinline__ ushort_t f2bf(float f) {
    union { float f; uint32 u; } x; x.f = f;
    uint32 r = (x.u + 0x7fffu + ((x.u >> 16) & 1u)) >> 16;
    return (ushort_t)r;
}

// async global->LDS, 16B per lane. lds must be wave-uniform base; HW adds lane*16.
__device__ __forceinline__ void gld16(ushort_t* lds, const ushort_t* g) {
    __builtin_amdgcn_global_load_lds(
        (const __attribute__((address_space(1))) uint32*)g,
        (__attribute__((address_space(3))) uint32*)lds,
        16, 0, 0);
}

// ---------------------------------------------------------------------------
__global__ __launch_bounds__(64) void lambda_kernel(
    const float* __restrict__ lq1, const float* __restrict__ lk1,
    const float* __restrict__ lq2, const float* __restrict__ lk2,
    float* __restrict__ lam)
{
    int l = threadIdx.x;
    float p1 = lq1[l] * lk1[l];
    float p2 = lq2[l] * lk2[l];
    for (int off = 32; off; off >>= 1) {
        p1 += __shfl_down(p1, off);
        p2 += __shfl_down(p2, off);
    }
    if (l == 0) lam[0] = expf(p1) - expf(p2) + LAMBDA_INIT_F;
}

// g[tau] = irfft(gaussian filter)[tau], exact via fp64 cosine sum
__global__ __launch_bounds__(64) void gfilt_kernel(float* __restrict__ g)
{
    int tau = blockIdx.x * 64 + threadIdx.x;
    double acc = 0.0;
    for (int k = 0; k <= 1024; ++k) {
        double w = (k == 0 || k == 1024) ? 1.0 : 2.0;
        double xk = (double)k * (1.0 / 1024.0);
        double r = xk * (1.0 / 0.15);
        double f = exp(-0.5 * r * r);
        int m = (k * tau) & 2047;
        double ang = (double)m * (6.283185307179586476925287 / 2048.0);
        acc += w * f * cos(ang);
    }
    g[tau] = (float)(acc * (1.0 / 2048.0));
}

// rotary tables: ct/st[t*32 + i] = cos/sin(t * 10000^(-i/32))
__global__ __launch_bounds__(256) void rottab(float* __restrict__ ct, float* __restrict__ st)
{
    int id = blockIdx.x * 256 + threadIdx.x;
    int t = id >> 5, i = id & 31;
    double inv = exp(-0.28782313662425575 * (double)i);  // ln(1e4)/32
    double a = (double)t * inv;
    ct[id] = (float)cos(a);
    st[id] = (float)sin(a);
}

// fp32 -> bf16 elementwise (8/thread)
__global__ __launch_bounds__(256) void cvt_bf16(const float* __restrict__ s, ushort_t* __restrict__ d)
{
    int i = (blockIdx.x * 256 + threadIdx.x) * 8;
    float4 a = *(const float4*)(s + i);
    float4 b = *(const float4*)(s + i + 4);
    uint4 pk;
    pk.x = (uint32)f2bf(a.x) | ((uint32)f2bf(a.y) << 16);
    pk.y = (uint32)f2bf(a.z) | ((uint32)f2bf(a.w) << 16);
    pk.z = (uint32)f2bf(b.x) | ((uint32)f2bf(b.y) << 16);
    pk.w = (uint32)f2bf(b.z) | ((uint32)f2bf(b.w) << 16);
    *(uint4*)(d + i) = pk;
}

// Transpose W[k][n] fp32 -> WT[n'][k] bf16. For z<2 (Wq,Wk) permute n within each
// 64-col head2 group: n' = head2*64 + (d&1)*32 + (d>>1)  (de-interleave rotary pairs)
__global__ __launch_bounds__(256) void wtrans(
    const float* __restrict__ Wq, const float* __restrict__ Wk,
    const float* __restrict__ Wv, const float* __restrict__ Wo,
    ushort_t* __restrict__ Tq, ushort_t* __restrict__ Tk,
    ushort_t* __restrict__ Tv, ushort_t* __restrict__ To)
{
    int z = blockIdx.z;
    const float* S = (z == 0) ? Wq : (z == 1) ? Wk : (z == 2) ? Wv : Wo;
    ushort_t* Dt = (z == 0) ? Tq : (z == 1) ? Tk : (z == 2) ? Tv : To;
    bool perm = (z < 2);
    __shared__ float Ls[64 * 65];
    const int tid = threadIdx.x;
    const int n0 = blockIdx.x * 64, k0 = blockIdx.y * 64;
    #pragma unroll
    for (int it = 0; it < 4; ++it) {
        int kk = it * 16 + (tid >> 4);
        int nn = (tid & 15) * 4;
        float4 v = *(const float4*)(S + (size_t)(k0 + kk) * 2048 + n0 + nn);
        Ls[(nn + 0) * 65 + kk] = v.x;
        Ls[(nn + 1) * 65 + kk] = v.y;
        Ls[(nn + 2) * 65 + kk] = v.z;
        Ls[(nn + 3) * 65 + kk] = v.w;
    }
    __syncthreads();
    int nl = tid >> 2, kc = (tid & 3) * 16;
    int ng = n0 + nl;
    int nd = perm ? ((ng & ~63) | ((ng & 1) << 5) | ((ng & 63) >> 1)) : ng;
    uint4 p0, p1;
    const float* row = Ls + nl * 65 + kc;
    p0.x = (uint32)f2bf(row[0])  | ((uint32)f2bf(row[1])  << 16);
    p0.y = (uint32)f2bf(row[2])  | ((uint32)f2bf(row[3])  << 16);
    p0.z = (uint32)f2bf(row[4])  | ((uint32)f2bf(row[5])  << 16);
    p0.w = (uint32)f2bf(row[6])  | ((uint32)f2bf(row[7])  << 16);
    p1.x = (uint32)f2bf(row[8])  | ((uint32)f2bf(row[9])  << 16);
    p1.y = (uint32)f2bf(row[10]) | ((uint32)f2bf(row[11]) << 16);
    p1.z = (uint32)f2bf(row[12]) | ((uint32)f2bf(row[13]) << 16);
    p1.w = (uint32)f2bf(row[14]) | ((uint32)f2bf(row[15]) << 16);
    *(uint4*)(Dt + (size_t)nd * 2048 + k0 + kc) = p0;
    *(uint4*)(Dt + (size_t)nd * 2048 + k0 + kc + 8) = p1;
}

// ---------------------------------------------------------------------------
// bf16 MFMA GEMM, 128x128 tile, BK=64, global_load_lds staging with XOR chunk swizzle.
// A[m][k] bf16 (lda 2048), BT[n][k] bf16 (ldb 2048).
template<int MODE>
__global__ __launch_bounds__(256) void gemm_bf16(
    const ushort_t* __restrict__ A, const ushort_t* __restrict__ BT,
    float* __restrict__ Cout, ushort_t* __restrict__ o1, ushort_t* __restrict__ o2,
    const float* __restrict__ ctab, const float* __restrict__ stab)
{
    __shared__ ushort_t As[8192];
    __shared__ ushort_t Bs[8192];
    const int tid = threadIdx.x;
    const int w = tid >> 6, lane = tid & 63;
    const int quad = lane >> 4, l15 = lane & 15;
    const int wr = w >> 1, wc = w & 1;
    const int rb = blockIdx.y * 128, cb = blockIdx.x * 128;

    f32x4 acc[4][4];
    #pragma unroll
    for (int i = 0; i < 4; ++i)
        #pragma unroll
        for (int j = 0; j < 4; ++j) acc[i][j] = (f32x4)0.0f;

    for (int k0 = 0; k0 < 2048; k0 += 64) {
        #pragma unroll
        for (int u = 0; u < 4; ++u) {
            int off = (w * 4 + u) * 512;
            int Lc = (off >> 3) + lane;
            int row = Lc >> 3, cc = (Lc & 7) ^ (row & 7);
            gld16(As + off, A + (size_t)(rb + row) * 2048 + k0 + cc * 8);
            gld16(Bs + off, BT + (size_t)(cb + row) * 2048 + k0 + cc * 8);
        }
        __syncthreads();
        #pragma unroll
        for (int ks = 0; ks < 2; ++ks) {
            short8 af[4], bfr[4];
            #pragma unroll
            for (int mi = 0; mi < 4; ++mi) {
                int r = wr * 64 + mi * 16 + l15;
                af[mi] = *(const short8*)(As + r * 64 + ((ks * 4 + quad) ^ (r & 7)) * 8);
            }
            #pragma unroll
            for (int nj = 0; nj < 4; ++nj) {
                int r = wc * 64 + nj * 16 + l15;
                bfr[nj] = *(const short8*)(Bs + r * 64 + ((ks * 4 + quad) ^ (r & 7)) * 8);
            }
            #pragma unroll
            for (int mi = 0; mi < 4; ++mi)
                #pragma unroll
                for (int nj = 0; nj < 4; ++nj)
                    acc[mi][nj] = __builtin_amdgcn_mfma_f32_16x16x32_bf16(
                        af[mi], bfr[nj], acc[mi][nj], 0, 0, 0);
        }
        __syncthreads();
    }

    if (MODE == MODE_PLAIN) {
        #pragma unroll
        for (int mi = 0; mi < 4; ++mi)
            #pragma unroll
            for (int nj = 0; nj < 4; ++nj) {
                int cg = cb + wc * 64 + nj * 16 + l15;
                #pragma unroll
                for (int r = 0; r < 4; ++r) {
                    int t = rb + wr * 64 + mi * 16 + quad * 4 + r;
                    Cout[(size_t)t * 2048 + cg] = acc[mi][nj][r];
                }
            }
    } else if (MODE == MODE_QK) {
        // wave's 64 cols == one head2 group; cols [0,32)=x1_i, [32,64)=x2_i
        int head2 = (cb + wc * 64) >> 6;
        ushort_t* dst = ((head2 & 1) ? o2 : o1) + (size_t)(head2 >> 1) * 2048 * 64;
        #pragma unroll
        for (int mi = 0; mi < 4; ++mi)
            #pragma unroll
            for (int r = 0; r < 4; ++r) {
                int t = rb + wr * 64 + mi * 16 + quad * 4 + r;
                const float* ctr = ctab + t * 32;
                const float* str = stab + t * 32;
                #pragma unroll
                for (int nj = 0; nj < 2; ++nj) {
                    int i = nj * 16 + l15;
                    float c = ctr[i], s = str[i];
                    float x1 = acc[mi][nj][r], x2 = acc[mi][nj + 2][r];
                    dst[(size_t)t * 64 + i]      = f2bf(x1 * c - x2 * s);
                    dst[(size_t)t * 64 + 32 + i] = f2bf(x1 * s + x2 * c);
                }
            }
    } else { // MODE_V: write V^T [h][d][t] bf16, 4 t-consecutive packed per store
        #pragma unroll
        for (int mi = 0; mi < 4; ++mi)
            #pragma unroll
            for (int nj = 0; nj < 4; ++nj) {
                int cg = cb + wc * 64 + nj * 16 + l15;
                int hh = cg >> 7, pr = (cg >> 6) & 1, d = cg & 63;
                int tb = rb + wr * 64 + mi * 16 + quad * 4;
                ushort_t* dst = (pr ? o2 : o1) + ((size_t)(hh * 64 + d)) * 2048 + tb;
                u64 pk = (u64)f2bf(acc[mi][nj][0])
                       | ((u64)f2bf(acc[mi][nj][1]) << 16)
                       | ((u64)f2bf(acc[mi][nj][2]) << 32)
                       | ((u64)f2bf(acc[mi][nj][3]) << 48);
                *(u64*)dst = pk;
            }
    }
}

// ---------------------------------------------------------------------------
// MFMA flash attention. q,k: [h][t][64] bf16 (rotary-ordered d'); v1T,v2T: [h][64][2048] bf16.
// Computes S^T = K*Q^T so each lane owns one q-row's scores (cheap softmax),
// P -> LDS (packed b64 writes) -> A-operand for O = P*V.
__global__ __launch_bounds__(256) void attn_mfma(
    const ushort_t* __restrict__ q, const ushort_t* __restrict__ k,
    const ushort_t* __restrict__ v1T, const ushort_t* __restrict__ v2T,
    float* __restrict__ X, const float* __restrict__ lam_ptr, int combine)
{
    __shared__ ushort_t Qs[4096];
    __shared__ ushort_t Ks[4096];
    __shared__ ushort_t V1s[4096];
    __shared__ ushort_t V2s[4096];
    __shared__ ushort_t Ps[4][1280];  // per-wave P[16][80]

    const int tid = threadIdx.x;
    const int w = tid >> 6, lane = tid & 63;
    const int quad = lane >> 4, l15 = lane & 15;
    const int h = blockIdx.y;
    const int qt = 31 - blockIdx.x;   // heavy blocks dispatched first
    const float lam = combine ? lam_ptr[0] : 0.0f;

    // stage Q tile (contiguous 8KB)
    {
        const ushort_t* qtile = q + ((size_t)h * 2048 + qt * 64) * 64;
        #pragma unroll
        for (int u = 0; u < 2; ++u) {
            int off = (w * 2 + u) * 512;
            int Lc = (off >> 3) + lane;
            int row = Lc >> 3, cc = (Lc & 7) ^ (row & 7);
            gld16(Qs + off, qtile + row * 64 + cc * 8);
        }
    }
    __syncthreads();

    short8 qb[2];
    {
        int r = w * 16 + l15;
        qb[0] = *(const short8*)(Qs + r * 64 + ((quad) ^ (r & 7)) * 8);
        qb[1] = *(const short8*)(Qs + r * 64 + ((4 + quad) ^ (r & 7)) * 8);
    }

    f32x4 O[8];
    #pragma unroll
    for (int i = 0; i < 8; ++i) O[i] = (f32x4)0.0f;
    float m_i = -1e30f, l_i = 0.0f;
    const int row_g = qt * 64 + w * 16 + l15;

    for (int kt = 0; kt <= qt; ++kt) {
        __syncthreads();
        {
            const ushort_t* ktile = k + ((size_t)h * 2048 + kt * 64) * 64;
            #pragma unroll
            for (int u = 0; u < 2; ++u) {
                int off = (w * 2 + u) * 512;
                int Lc = (off >> 3) + lane;
                int row = Lc >> 3, cc = (Lc & 7) ^ (row & 7);
                gld16(Ks + off, ktile + row * 64 + cc * 8);
                gld16(V1s + off, v1T + ((size_t)(h * 64 + row)) * 2048 + kt * 64 + cc * 8);
                gld16(V2s + off, v2T + ((size_t)(h * 64 + row)) * 2048 + kt * 64 + cc * 8);
            }
        }
        __syncthreads();

        // S^T = K * Q^T : lane col = q-row (l15), rows = kpos
        f32x4 s[4];
        #pragma unroll
        for (int j = 0; j < 4; ++j) s[j] = (f32x4)0.0f;
        #pragma unroll
        for (int ks = 0; ks < 2; ++ks)
            #pragma unroll
            for (int j = 0; j < 4; ++j) {
                int r = j * 16 + l15;
                short8 kf = *(const short8*)(Ks + r * 64 + ((ks * 4 + quad) ^ (r & 7)) * 8);
                s[j] = __builtin_amdgcn_mfma_f32_16x16x32_bf16(kf, qb[ks], s[j], 0, 0, 0);
            }

        // online softmax (all 16 values in this lane belong to q-row l15)
        float pv[16];
        float mx = -1e30f;
        #pragma unroll
        for (int j = 0; j < 4; ++j)
            #pragma unroll
            for (int r = 0; r < 4; ++r) {
                int kpos = kt * 64 + j * 16 + quad * 4 + r;
                float v = s[j][r] * 0.125f;
                v = (kpos <= row_g) ? v : -1e30f;
                pv[j * 4 + r] = v;
                mx = fmaxf(mx, v);
            }
        mx = fmaxf(mx, __shfl_xor(mx, 16));
        mx = fmaxf(mx, __shfl_xor(mx, 32));
        float newm = fmaxf(m_i, mx);
        float alpha = __expf(m_i - newm);
        float sum = 0.0f;
        ushort_t pb[16];
        #pragma unroll
        for (int i = 0; i < 16; ++i) {
            float p = __expf(pv[i] - newm);
            sum += p;
            pb[i] = f2bf(p);
        }
        sum += __shfl_xor(sum, 16);
        sum += __shfl_xor(sum, 32);
        l_i = l_i * alpha + sum;
        m_i = newm;

        // P[row=l15][kpos] to LDS, 4x packed b64
        ushort_t* pw = Ps[w];
        #pragma unroll
        for (int j = 0; j < 4; ++j) {
            u64 pk = (u64)pb[j * 4] | ((u64)pb[j * 4 + 1] << 16)
                   | ((u64)pb[j * 4 + 2] << 32) | ((u64)pb[j * 4 + 3] << 48);
            *(u64*)(pw + l15 * 80 + j * 16 + quad * 4) = pk;
        }

        // rescale O (C-layout rows = quad*4+r; alpha lives in lane quad*4+r)
        float av0 = __shfl(alpha, quad * 4 + 0);
        float av1 = __shfl(alpha, quad * 4 + 1);
        float av2 = __shfl(alpha, quad * 4 + 2);
        float av3 = __shfl(alpha, quad * 4 + 3);
        #pragma unroll
        for (int nt = 0; nt < 8; ++nt) {
            O[nt][0] *= av0; O[nt][1] *= av1; O[nt][2] *= av2; O[nt][3] *= av3;
        }

        // O += P * V
        #pragma unroll
        for (int ks = 0; ks < 2; ++ks) {
            short8 pf = *(const short8*)(pw + l15 * 80 + ks * 32 + quad * 8);
            #pragma unroll
            for (int nt = 0; nt < 8; ++nt) {
                const ushort_t* Vs = (nt < 4) ? V1s : V2s;
                int d = (nt & 3) * 16 + l15;
                short8 vf = *(const short8*)(Vs + d * 64 + ((ks * 4 + quad) ^ (d & 7)) * 8);
                O[nt] = __builtin_amdgcn_mfma_f32_16x16x32_bf16(pf, vf, O[nt], 0, 0, 0);
            }
        }
    }

    // epilogue
    float lv0 = __shfl(l_i, quad * 4 + 0);
    float lv1 = __shfl(l_i, quad * 4 + 1);
    float lv2 = __shfl(l_i, quad * 4 + 2);
    float lv3 = __shfl(l_i, quad * 4 + 3);
    float r0 = 1.0f / lv0, r1 = 1.0f / lv1, r2 = 1.0f / lv2, r3 = 1.0f / lv3;
    int tb = qt * 64 + w * 16 + quad * 4;
    #pragma unroll
    for (int nt = 0; nt < 8; ++nt) {
        int col = h * 128 + nt * 16 + l15;
        float v0 = O[nt][0] * r0, v1 = O[nt][1] * r1, v2 = O[nt][2] * r2, v3 = O[nt][3] * r3;
        if (!combine) {
            X[(size_t)(tb + 0) * 2048 + col] = v0;
            X[(size_t)(tb + 1) * 2048 + col] = v1;
            X[(size_t)(tb + 2) * 2048 + col] = v2;
            X[(size_t)(tb + 3) * 2048 + col] = v3;
        } else {
            size_t a0 = (size_t)(tb + 0) * 2048 + col;
            size_t a1 = (size_t)(tb + 1) * 2048 + col;
            size_t a2 = (size_t)(tb + 2) * 2048 + col;
            size_t a3 = (size_t)(tb + 3) * 2048 + col;
            X[a0] -= lam * v0; X[a1] -= lam * v1; X[a2] -= lam * v2; X[a3] -= lam * v3;
        }
    }
}

// ---------------------------------------------------------------------------
// LDS-tiled truncated circular conv along t (129 taps)
__global__ __launch_bounds__(256) void conv_t(
    const float* __restrict__ X, const float* __restrict__ g, float* __restrict__ Y)
{
    __shared__ float Xs[192 * 64];
    __shared__ float gs[129];
    const int tid = threadIdx.x;
    const int c0 = blockIdx.x * 64, t0 = blockIdx.y * 64;
    const int c = tid & 63, tg = tid >> 6;
    for (int j = tg; j < 192; j += 4)
        Xs[j * 64 + c] = X[(size_t)((t0 - 64 + j) & 2047) * 2048 + c0 + c];
    if (tid < 129) gs[tid] = g[(tid - 64) & 2047];
    __syncthreads();
    float accv[16];
    #pragma unroll
    for (int i = 0; i < 16; ++i) accv[i] = 0.0f;
    const int tl0 = tg * 16;
    for (int tap = 0; tap < 129; ++tap) {
        float gv = gs[tap];
        int base = (tl0 + 128 - tap) * 64 + c;
        #pragma unroll
        for (int i = 0; i < 16; ++i) accv[i] += gv * Xs[base + i * 64];
    }
    #pragma unroll
    for (int i = 0; i < 16; ++i)
        Y[(size_t)(t0 + tl0 + i) * 2048 + c0 + c] = accv[i];
}

// RMSNorm over 128 per (t,h); writes bf16 for the final GEMM
__global__ __launch_bounds__(64) void rms_bf(
    const float* __restrict__ Y, const float* __restrict__ wgt, ushort_t* __restrict__ yb)
{
    int grp = blockIdx.x;
    int t = grp >> 4, hh = grp & 15, l = threadIdx.x;
    size_t base = (size_t)t * 2048 + hh * 128;
    float a = Y[base + l];
    float b = Y[base + 64 + l];
    float ss = a * a + b * b;
    for (int off = 32; off; off >>= 1) ss += __shfl_down(ss, off);
    ss = __shfl(ss, 0);
    float r = rsqrtf(ss * (1.0f / 128.0f) + 1e-5f) * ONE_MINUS_LI;
    yb[base + l]      = f2bf(a * r * wgt[l]);
    yb[base + 64 + l] = f2bf(b * r * wgt[64 + l]);
}

// ---------------------------------------------------------------------------
extern "C" void kernel_launch(void* const* d_in, const int* in_sizes, int n_in,
                              void* d_out, int out_size, void* d_ws, size_t ws_size,
                              hipStream_t stream)
{
    const float* query = (const float*)d_in[0];
    const float* Wq    = (const float*)d_in[1];
    const float* Wk    = (const float*)d_in[2];
    const float* Wv    = (const float*)d_in[3];
    const float* Wout  = (const float*)d_in[4];
    const float* lq1   = (const float*)d_in[5];
    const float* lk1   = (const float*)d_in[6];
    const float* lq2   = (const float*)d_in[7];
    const float* lk2   = (const float*)d_in[8];
    const float* rmsw  = (const float*)d_in[9];
    float* out = (float*)d_out;

    const size_t MB = 1ull << 20;
    char* W = (char*)d_ws;
    ushort_t* WqT   = (ushort_t*)(W + 0 * MB);
    ushort_t* WkT   = (ushort_t*)(W + 8 * MB);
    ushort_t* WvT   = (ushort_t*)(W + 16 * MB);
    ushort_t* WoutT = (ushort_t*)(W + 24 * MB);
    ushort_t* qb    = (ushort_t*)(W + 32 * MB);
    ushort_t* q1    = (ushort_t*)(W + 40 * MB);
    ushort_t* q2    = (ushort_t*)(W + 44 * MB);
    ushort_t* k1    = (ushort_t*)(W + 48 * MB);
    ushort_t* k2    = (ushort_t*)(W + 52 * MB);
    ushort_t* v1T   = (ushort_t*)(W + 56 * MB);
    ushort_t* v2T   = (ushort_t*)(W + 60 * MB);
    float*    X     = (float*)   (W + 64 * MB);
    float*    Y     = (float*)   (W + 32 * MB);  // aliases qb/q1/q2 (dead by conv time)
    ushort_t* ybf   = (ushort_t*)(W + 48 * MB);  // aliases k1/k2 (dead by rms time)
    float*    ctab  = (float*)   (W + 80 * MB);
    float*    stab  = (float*)   (W + 80 * MB + 256 * 1024);
    float*    gbuf  = (float*)   (W + 80 * MB + 512 * 1024);
    float*    lam   = (float*)   (W + 80 * MB + 520 * 1024);

    lambda_kernel<<<1, 64, 0, stream>>>(lq1, lk1, lq2, lk2, lam);
    gfilt_kernel<<<32, 64, 0, stream>>>(gbuf);
    rottab<<<256, 256, 0, stream>>>(ctab, stab);
    cvt_bf16<<<2048, 256, 0, stream>>>(query, qb);
    wtrans<<<dim3(32, 32, 4), 256, 0, stream>>>(Wq, Wk, Wv, Wout, WqT, WkT, WvT, WoutT);

    dim3 ggrid(16, 16);
    gemm_bf16<MODE_QK><<<ggrid, 256, 0, stream>>>(qb, WqT, nullptr, q1, q2, ctab, stab);
    gemm_bf16<MODE_QK><<<ggrid, 256, 0, stream>>>(qb, WkT, nullptr, k1, k2, ctab, stab);
    gemm_bf16<MODE_V><<<ggrid, 256, 0, stream>>>(qb, WvT, nullptr, v1T, v2T, nullptr, nullptr);

    dim3 agrid(32, 16);
    attn_mfma<<<agrid, 256, 0, stream>>>(q1, k1, v1T, v2T, X, lam, 0);
    attn_mfma<<<agrid, 256, 0, stream>>>(q2, k2, v1T, v2T, X, lam, 1);

    conv_t<<<dim3(32, 32), 256, 0, stream>>>(X, gbuf, Y);
    rms_bf<<<32768, 64, 0, stream>>>(Y, rmsw, ybf);

    gemm_bf16<MODE_PLAIN><<<ggrid, 256, 0, stream>>>(ybf, WoutT, out, nullptr, nullptr, nullptr, nullptr);
}

// Round 3
// 469.094 us; speedup vs baseline: 8.2765x; 1.5484x over previous
//
#include <hip/hip_runtime.h>
#include <math.h>

#define MODE_PLAIN 0
#define MODE_QK    1
#define MODE_V     2

#define LAMBDA_INIT_F 0.7836057665316245f
#define ONE_MINUS_LI  0.2163942334683755f

typedef unsigned short ushort_t;
typedef unsigned int   uint32;
typedef unsigned long long u64;
typedef __attribute__((ext_vector_type(8))) short short8;
typedef __attribute__((ext_vector_type(4))) float f32x4;

// float -> bf16 (RNE)
__device__ __forceinline__ ushort_t f2bf(float f) {
    union { float f; uint32 u; } x; x.f = f;
    uint32 r = (x.u + 0x7fffu + ((x.u >> 16) & 1u)) >> 16;
    return (ushort_t)r;
}

// async global->LDS, 16B per lane. lds must be wave-uniform base; HW adds lane*16.
__device__ __forceinline__ void gld16(ushort_t* lds, const ushort_t* g) {
    __builtin_amdgcn_global_load_lds(
        (const __attribute__((address_space(1))) uint32*)g,
        (__attribute__((address_space(3))) uint32*)lds,
        16, 0, 0);
}

// ---------------------------------------------------------------------------
__global__ __launch_bounds__(64) void lambda_kernel(
    const float* __restrict__ lq1, const float* __restrict__ lk1,
    const float* __restrict__ lq2, const float* __restrict__ lk2,
    float* __restrict__ lam)
{
    int l = threadIdx.x;
    float p1 = lq1[l] * lk1[l];
    float p2 = lq2[l] * lk2[l];
    for (int off = 32; off; off >>= 1) {
        p1 += __shfl_down(p1, off);
        p2 += __shfl_down(p2, off);
    }
    if (l == 0) lam[0] = expf(p1) - expf(p2) + LAMBDA_INIT_F;
}

// g[j] = irfft(gaussian filter)[tau=j-64], j in [0,129).
// Parallel k-sum: 256 threads handle k = tid, tid+256, ... (<=1024), fp32 with
// exact integer phase reduction; wave + LDS reduce.
__global__ __launch_bounds__(256) void gfilt_kernel(float* __restrict__ g)
{
    __shared__ float red[4];
    const int j = blockIdx.x;            // 0..128
    int tau = j - 64;
    int ta = tau < 0 ? -tau : tau;       // cos is even
    const int tid = threadIdx.x;
    float acc = 0.0f;
    for (int k = tid; k <= 1024; k += 256) {
        float w = (k == 0 || k == 1024) ? 1.0f : 2.0f;
        float r = (float)k * (1.0f / 153.6f);     // (k/1024)/0.15
        float f = expf(-0.5f * r * r);
        int m = (k * ta) & 2047;                  // exact phase mod
        float ang = (float)m * 3.0679615757712823e-3f;  // 2*pi/2048
        acc += w * f * cosf(ang);
    }
    for (int off = 32; off; off >>= 1) acc += __shfl_down(acc, off);
    if ((tid & 63) == 0) red[tid >> 6] = acc;
    __syncthreads();
    if (tid == 0)
        g[j] = (red[0] + red[1] + red[2] + red[3]) * (1.0f / 2048.0f);
}

// rotary tables: ct/st[t*32 + i] = cos/sin(t * 10000^(-i/32))
__global__ __launch_bounds__(256) void rottab(float* __restrict__ ct, float* __restrict__ st)
{
    int id = blockIdx.x * 256 + threadIdx.x;
    int t = id >> 5, i = id & 31;
    double inv = exp(-0.28782313662425575 * (double)i);  // ln(1e4)/32
    double a = (double)t * inv;
    ct[id] = (float)cos(a);
    st[id] = (float)sin(a);
}

// fp32 -> bf16 elementwise (8/thread)
__global__ __launch_bounds__(256) void cvt_bf16(const float* __restrict__ s, ushort_t* __restrict__ d)
{
    int i = (blockIdx.x * 256 + threadIdx.x) * 8;
    float4 a = *(const float4*)(s + i);
    float4 b = *(const float4*)(s + i + 4);
    uint4 pk;
    pk.x = (uint32)f2bf(a.x) | ((uint32)f2bf(a.y) << 16);
    pk.y = (uint32)f2bf(a.z) | ((uint32)f2bf(a.w) << 16);
    pk.z = (uint32)f2bf(b.x) | ((uint32)f2bf(b.y) << 16);
    pk.w = (uint32)f2bf(b.z) | ((uint32)f2bf(b.w) << 16);
    *(uint4*)(d + i) = pk;
}

// Transpose W[k][n] fp32 -> WT[n'][k] bf16. For z<2 (Wq,Wk) permute n within each
// 64-col head2 group: n' = head2*64 + (d&1)*32 + (d>>1)  (de-interleave rotary pairs)
__global__ __launch_bounds__(256) void wtrans(
    const float* __restrict__ Wq, const float* __restrict__ Wk,
    const float* __restrict__ Wv, const float* __restrict__ Wo,
    ushort_t* __restrict__ Tq, ushort_t* __restrict__ Tk,
    ushort_t* __restrict__ Tv, ushort_t* __restrict__ To)
{
    int z = blockIdx.z;
    const float* S = (z == 0) ? Wq : (z == 1) ? Wk : (z == 2) ? Wv : Wo;
    ushort_t* Dt = (z == 0) ? Tq : (z == 1) ? Tk : (z == 2) ? Tv : To;
    bool perm = (z < 2);
    __shared__ float Ls[64 * 65];
    const int tid = threadIdx.x;
    const int n0 = blockIdx.x * 64, k0 = blockIdx.y * 64;
    #pragma unroll
    for (int it = 0; it < 4; ++it) {
        int kk = it * 16 + (tid >> 4);
        int nn = (tid & 15) * 4;
        float4 v = *(const float4*)(S + (size_t)(k0 + kk) * 2048 + n0 + nn);
        Ls[(nn + 0) * 65 + kk] = v.x;
        Ls[(nn + 1) * 65 + kk] = v.y;
        Ls[(nn + 2) * 65 + kk] = v.z;
        Ls[(nn + 3) * 65 + kk] = v.w;
    }
    __syncthreads();
    int nl = tid >> 2, kc = (tid & 3) * 16;
    int ng = n0 + nl;
    int nd = perm ? ((ng & ~63) | ((ng & 1) << 5) | ((ng & 63) >> 1)) : ng;
    uint4 p0, p1;
    const float* row = Ls + nl * 65 + kc;
    p0.x = (uint32)f2bf(row[0])  | ((uint32)f2bf(row[1])  << 16);
    p0.y = (uint32)f2bf(row[2])  | ((uint32)f2bf(row[3])  << 16);
    p0.z = (uint32)f2bf(row[4])  | ((uint32)f2bf(row[5])  << 16);
    p0.w = (uint32)f2bf(row[6])  | ((uint32)f2bf(row[7])  << 16);
    p1.x = (uint32)f2bf(row[8])  | ((uint32)f2bf(row[9])  << 16);
    p1.y = (uint32)f2bf(row[10]) | ((uint32)f2bf(row[11]) << 16);
    p1.z = (uint32)f2bf(row[12]) | ((uint32)f2bf(row[13]) << 16);
    p1.w = (uint32)f2bf(row[14]) | ((uint32)f2bf(row[15]) << 16);
    *(uint4*)(Dt + (size_t)nd * 2048 + k0 + kc) = p0;
    *(uint4*)(Dt + (size_t)nd * 2048 + k0 + kc + 8) = p1;
}

// ---------------------------------------------------------------------------
// bf16 MFMA GEMM, 128x128 tile, BK=64, global_load_lds staging with XOR chunk swizzle.
// A[m][k] bf16 (lda 2048), BT[n][k] bf16 (ldb 2048).
template<int MODE>
__global__ __launch_bounds__(256) void gemm_bf16(
    const ushort_t* __restrict__ A, const ushort_t* __restrict__ BT,
    float* __restrict__ Cout, ushort_t* __restrict__ o1, ushort_t* __restrict__ o2,
    const float* __restrict__ ctab, const float* __restrict__ stab)
{
    __shared__ ushort_t As[8192];
    __shared__ ushort_t Bs[8192];
    const int tid = threadIdx.x;
    const int w = tid >> 6, lane = tid & 63;
    const int quad = lane >> 4, l15 = lane & 15;
    const int wr = w >> 1, wc = w & 1;
    const int rb = blockIdx.y * 128, cb = blockIdx.x * 128;

    f32x4 acc[4][4];
    #pragma unroll
    for (int i = 0; i < 4; ++i)
        #pragma unroll
        for (int j = 0; j < 4; ++j) acc[i][j] = (f32x4)0.0f;

    for (int k0 = 0; k0 < 2048; k0 += 64) {
        #pragma unroll
        for (int u = 0; u < 4; ++u) {
            int off = (w * 4 + u) * 512;
            int Lc = (off >> 3) + lane;
            int row = Lc >> 3, cc = (Lc & 7) ^ (row & 7);
            gld16(As + off, A + (size_t)(rb + row) * 2048 + k0 + cc * 8);
            gld16(Bs + off, BT + (size_t)(cb + row) * 2048 + k0 + cc * 8);
        }
        __syncthreads();
        #pragma unroll
        for (int ks = 0; ks < 2; ++ks) {
            short8 af[4], bfr[4];
            #pragma unroll
            for (int mi = 0; mi < 4; ++mi) {
                int r = wr * 64 + mi * 16 + l15;
                af[mi] = *(const short8*)(As + r * 64 + ((ks * 4 + quad) ^ (r & 7)) * 8);
            }
            #pragma unroll
            for (int nj = 0; nj < 4; ++nj) {
                int r = wc * 64 + nj * 16 + l15;
                bfr[nj] = *(const short8*)(Bs + r * 64 + ((ks * 4 + quad) ^ (r & 7)) * 8);
            }
            #pragma unroll
            for (int mi = 0; mi < 4; ++mi)
                #pragma unroll
                for (int nj = 0; nj < 4; ++nj)
                    acc[mi][nj] = __builtin_amdgcn_mfma_f32_16x16x32_bf16(
                        af[mi], bfr[nj], acc[mi][nj], 0, 0, 0);
        }
        __syncthreads();
    }

    if (MODE == MODE_PLAIN) {
        #pragma unroll
        for (int mi = 0; mi < 4; ++mi)
            #pragma unroll
            for (int nj = 0; nj < 4; ++nj) {
                int cg = cb + wc * 64 + nj * 16 + l15;
                #pragma unroll
                for (int r = 0; r < 4; ++r) {
                    int t = rb + wr * 64 + mi * 16 + quad * 4 + r;
                    Cout[(size_t)t * 2048 + cg] = acc[mi][nj][r];
                }
            }
    } else if (MODE == MODE_QK) {
        // wave's 64 cols == one head2 group; cols [0,32)=x1_i, [32,64)=x2_i
        int head2 = (cb + wc * 64) >> 6;
        ushort_t* dst = ((head2 & 1) ? o2 : o1) + (size_t)(head2 >> 1) * 2048 * 64;
        #pragma unroll
        for (int mi = 0; mi < 4; ++mi)
            #pragma unroll
            for (int r = 0; r < 4; ++r) {
                int t = rb + wr * 64 + mi * 16 + quad * 4 + r;
                const float* ctr = ctab + t * 32;
                const float* str = stab + t * 32;
                #pragma unroll
                for (int nj = 0; nj < 2; ++nj) {
                    int i = nj * 16 + l15;
                    float c = ctr[i], s = str[i];
                    float x1 = acc[mi][nj][r], x2 = acc[mi][nj + 2][r];
                    dst[(size_t)t * 64 + i]      = f2bf(x1 * c - x2 * s);
                    dst[(size_t)t * 64 + 32 + i] = f2bf(x1 * s + x2 * c);
                }
            }
    } else { // MODE_V: write V^T [h][d][t] bf16, 4 t-consecutive packed per store
        #pragma unroll
        for (int mi = 0; mi < 4; ++mi)
            #pragma unroll
            for (int nj = 0; nj < 4; ++nj) {
                int cg = cb + wc * 64 + nj * 16 + l15;
                int hh = cg >> 7, pr = (cg >> 6) & 1, d = cg & 63;
                int tb = rb + wr * 64 + mi * 16 + quad * 4;
                ushort_t* dst = (pr ? o2 : o1) + ((size_t)(hh * 64 + d)) * 2048 + tb;
                u64 pk = (u64)f2bf(acc[mi][nj][0])
                       | ((u64)f2bf(acc[mi][nj][1]) << 16)
                       | ((u64)f2bf(acc[mi][nj][2]) << 32)
                       | ((u64)f2bf(acc[mi][nj][3]) << 48);
                *(u64*)dst = pk;
            }
    }
}

// ---------------------------------------------------------------------------
// MFMA flash attention. q,k: [h][t][64] bf16 (rotary-ordered d'); v1T,v2T: [h][64][2048] bf16.
// Computes S^T = K*Q^T so each lane owns one q-row's scores (cheap softmax),
// P -> LDS (packed b64 writes) -> A-operand for O = P*V.
__global__ __launch_bounds__(256) void attn_mfma(
    const ushort_t* __restrict__ q, const ushort_t* __restrict__ k,
    const ushort_t* __restrict__ v1T, const ushort_t* __restrict__ v2T,
    float* __restrict__ X, const float* __restrict__ lam_ptr, int combine)
{
    __shared__ ushort_t Qs[4096];
    __shared__ ushort_t Ks[4096];
    __shared__ ushort_t V1s[4096];
    __shared__ ushort_t V2s[4096];
    __shared__ ushort_t Ps[4][1280];  // per-wave P[16][80]

    const int tid = threadIdx.x;
    const int w = tid >> 6, lane = tid & 63;
    const int quad = lane >> 4, l15 = lane & 15;
    const int h = blockIdx.y;
    const int qt = 31 - blockIdx.x;   // heavy blocks dispatched first
    const float lam = combine ? lam_ptr[0] : 0.0f;

    // stage Q tile (contiguous 8KB)
    {
        const ushort_t* qtile = q + ((size_t)h * 2048 + qt * 64) * 64;
        #pragma unroll
        for (int u = 0; u < 2; ++u) {
            int off = (w * 2 + u) * 512;
            int Lc = (off >> 3) + lane;
            int row = Lc >> 3, cc = (Lc & 7) ^ (row & 7);
            gld16(Qs + off, qtile + row * 64 + cc * 8);
        }
    }
    __syncthreads();

    short8 qb[2];
    {
        int r = w * 16 + l15;
        qb[0] = *(const short8*)(Qs + r * 64 + ((quad) ^ (r & 7)) * 8);
        qb[1] = *(const short8*)(Qs + r * 64 + ((4 + quad) ^ (r & 7)) * 8);
    }

    f32x4 O[8];
    #pragma unroll
    for (int i = 0; i < 8; ++i) O[i] = (f32x4)0.0f;
    float m_i = -1e30f, l_i = 0.0f;
    const int row_g = qt * 64 + w * 16 + l15;

    for (int kt = 0; kt <= qt; ++kt) {
        __syncthreads();
        {
            const ushort_t* ktile = k + ((size_t)h * 2048 + kt * 64) * 64;
            #pragma unroll
            for (int u = 0; u < 2; ++u) {
                int off = (w * 2 + u) * 512;
                int Lc = (off >> 3) + lane;
                int row = Lc >> 3, cc = (Lc & 7) ^ (row & 7);
                gld16(Ks + off, ktile + row * 64 + cc * 8);
                gld16(V1s + off, v1T + ((size_t)(h * 64 + row)) * 2048 + kt * 64 + cc * 8);
                gld16(V2s + off, v2T + ((size_t)(h * 64 + row)) * 2048 + kt * 64 + cc * 8);
            }
        }
        __syncthreads();

        // S^T = K * Q^T : lane col = q-row (l15), rows = kpos
        f32x4 s[4];
        #pragma unroll
        for (int j = 0; j < 4; ++j) s[j] = (f32x4)0.0f;
        #pragma unroll
        for (int ks = 0; ks < 2; ++ks)
            #pragma unroll
            for (int j = 0; j < 4; ++j) {
                int r = j * 16 + l15;
                short8 kf = *(const short8*)(Ks + r * 64 + ((ks * 4 + quad) ^ (r & 7)) * 8);
                s[j] = __builtin_amdgcn_mfma_f32_16x16x32_bf16(kf, qb[ks], s[j], 0, 0, 0);
            }

        // online softmax (all 16 values in this lane belong to q-row l15)
        float pv[16];
        float mx = -1e30f;
        #pragma unroll
        for (int j = 0; j < 4; ++j)
            #pragma unroll
            for (int r = 0; r < 4; ++r) {
                int kpos = kt * 64 + j * 16 + quad * 4 + r;
                float v = s[j][r] * 0.125f;
                v = (kpos <= row_g) ? v : -1e30f;
                pv[j * 4 + r] = v;
                mx = fmaxf(mx, v);
            }
        mx = fmaxf(mx, __shfl_xor(mx, 16));
        mx = fmaxf(mx, __shfl_xor(mx, 32));
        float newm = fmaxf(m_i, mx);
        float alpha = __expf(m_i - newm);
        float sum = 0.0f;
        ushort_t pb[16];
        #pragma unroll
        for (int i = 0; i < 16; ++i) {
            float p = __expf(pv[i] - newm);
            sum += p;
            pb[i] = f2bf(p);
        }
        sum += __shfl_xor(sum, 16);
        sum += __shfl_xor(sum, 32);
        l_i = l_i * alpha + sum;
        m_i = newm;

        // P[row=l15][kpos] to LDS, 4x packed b64
        ushort_t* pw = Ps[w];
        #pragma unroll
        for (int j = 0; j < 4; ++j) {
            u64 pk = (u64)pb[j * 4] | ((u64)pb[j * 4 + 1] << 16)
                   | ((u64)pb[j * 4 + 2] << 32) | ((u64)pb[j * 4 + 3] << 48);
            *(u64*)(pw + l15 * 80 + j * 16 + quad * 4) = pk;
        }

        // rescale O (C-layout rows = quad*4+r; alpha lives in lane quad*4+r)
        float av0 = __shfl(alpha, quad * 4 + 0);
        float av1 = __shfl(alpha, quad * 4 + 1);
        float av2 = __shfl(alpha, quad * 4 + 2);
        float av3 = __shfl(alpha, quad * 4 + 3);
        #pragma unroll
        for (int nt = 0; nt < 8; ++nt) {
            O[nt][0] *= av0; O[nt][1] *= av1; O[nt][2] *= av2; O[nt][3] *= av3;
        }

        // O += P * V
        #pragma unroll
        for (int ks = 0; ks < 2; ++ks) {
            short8 pf = *(const short8*)(pw + l15 * 80 + ks * 32 + quad * 8);
            #pragma unroll
            for (int nt = 0; nt < 8; ++nt) {
                const ushort_t* Vs = (nt < 4) ? V1s : V2s;
                int d = (nt & 3) * 16 + l15;
                short8 vf = *(const short8*)(Vs + d * 64 + ((ks * 4 + quad) ^ (d & 7)) * 8);
                O[nt] = __builtin_amdgcn_mfma_f32_16x16x32_bf16(pf, vf, O[nt], 0, 0, 0);
            }
        }
    }

    // epilogue
    float lv0 = __shfl(l_i, quad * 4 + 0);
    float lv1 = __shfl(l_i, quad * 4 + 1);
    float lv2 = __shfl(l_i, quad * 4 + 2);
    float lv3 = __shfl(l_i, quad * 4 + 3);
    float r0 = 1.0f / lv0, r1 = 1.0f / lv1, r2 = 1.0f / lv2, r3 = 1.0f / lv3;
    int tb = qt * 64 + w * 16 + quad * 4;
    #pragma unroll
    for (int nt = 0; nt < 8; ++nt) {
        int col = h * 128 + nt * 16 + l15;
        float v0 = O[nt][0] * r0, v1 = O[nt][1] * r1, v2 = O[nt][2] * r2, v3 = O[nt][3] * r3;
        if (!combine) {
            X[(size_t)(tb + 0) * 2048 + col] = v0;
            X[(size_t)(tb + 1) * 2048 + col] = v1;
            X[(size_t)(tb + 2) * 2048 + col] = v2;
            X[(size_t)(tb + 3) * 2048 + col] = v3;
        } else {
            size_t a0 = (size_t)(tb + 0) * 2048 + col;
            size_t a1 = (size_t)(tb + 1) * 2048 + col;
            size_t a2 = (size_t)(tb + 2) * 2048 + col;
            size_t a3 = (size_t)(tb + 3) * 2048 + col;
            X[a0] -= lam * v0; X[a1] -= lam * v1; X[a2] -= lam * v2; X[a3] -= lam * v3;
        }
    }
}

// ---------------------------------------------------------------------------
// LDS-tiled truncated circular conv along t (129 taps); g indexed g[j]=g(tau=j-64)
__global__ __launch_bounds__(256) void conv_t(
    const float* __restrict__ X, const float* __restrict__ g, float* __restrict__ Y)
{
    __shared__ float Xs[192 * 64];
    __shared__ float gs[129];
    const int tid = threadIdx.x;
    const int c0 = blockIdx.x * 64, t0 = blockIdx.y * 64;
    const int c = tid & 63, tg = tid >> 6;
    for (int j = tg; j < 192; j += 4)
        Xs[j * 64 + c] = X[(size_t)((t0 - 64 + j) & 2047) * 2048 + c0 + c];
    if (tid < 129) gs[tid] = g[tid];
    __syncthreads();
    float accv[16];
    #pragma unroll
    for (int i = 0; i < 16; ++i) accv[i] = 0.0f;
    const int tl0 = tg * 16;
    for (int tap = 0; tap < 129; ++tap) {
        float gv = gs[tap];
        int base = (tl0 + 128 - tap) * 64 + c;
        #pragma unroll
        for (int i = 0; i < 16; ++i) accv[i] += gv * Xs[base + i * 64];
    }
    #pragma unroll
    for (int i = 0; i < 16; ++i)
        Y[(size_t)(t0 + tl0 + i) * 2048 + c0 + c] = accv[i];
}

// RMSNorm over 128 per (t,h); writes bf16 for the final GEMM
__global__ __launch_bounds__(64) void rms_bf(
    const float* __restrict__ Y, const float* __restrict__ wgt, ushort_t* __restrict__ yb)
{
    int grp = blockIdx.x;
    int t = grp >> 4, hh = grp & 15, l = threadIdx.x;
    size_t base = (size_t)t * 2048 + hh * 128;
    float a = Y[base + l];
    float b = Y[base + 64 + l];
    float ss = a * a + b * b;
    for (int off = 32; off; off >>= 1) ss += __shfl_down(ss, off);
    ss = __shfl(ss, 0);
    float r = rsqrtf(ss * (1.0f / 128.0f) + 1e-5f) * ONE_MINUS_LI;
    yb[base + l]      = f2bf(a * r * wgt[l]);
    yb[base + 64 + l] = f2bf(b * r * wgt[64 + l]);
}

// ---------------------------------------------------------------------------
extern "C" void kernel_launch(void* const* d_in, const int* in_sizes, int n_in,
                              void* d_out, int out_size, void* d_ws, size_t ws_size,
                              hipStream_t stream)
{
    const float* query = (const float*)d_in[0];
    const float* Wq    = (const float*)d_in[1];
    const float* Wk    = (const float*)d_in[2];
    const float* Wv    = (const float*)d_in[3];
    const float* Wout  = (const float*)d_in[4];
    const float* lq1   = (const float*)d_in[5];
    const float* lk1   = (const float*)d_in[6];
    const float* lq2   = (const float*)d_in[7];
    const float* lk2   = (const float*)d_in[8];
    const float* rmsw  = (const float*)d_in[9];
    float* out = (float*)d_out;

    const size_t MB = 1ull << 20;
    char* W = (char*)d_ws;
    ushort_t* WqT   = (ushort_t*)(W + 0 * MB);
    ushort_t* WkT   = (ushort_t*)(W + 8 * MB);
    ushort_t* WvT   = (ushort_t*)(W + 16 * MB);
    ushort_t* WoutT = (ushort_t*)(W + 24 * MB);
    ushort_t* qb    = (ushort_t*)(W + 32 * MB);
    ushort_t* q1    = (ushort_t*)(W + 40 * MB);
    ushort_t* q2    = (ushort_t*)(W + 44 * MB);
    ushort_t* k1    = (ushort_t*)(W + 48 * MB);
    ushort_t* k2    = (ushort_t*)(W + 52 * MB);
    ushort_t* v1T   = (ushort_t*)(W + 56 * MB);
    ushort_t* v2T   = (ushort_t*)(W + 60 * MB);
    float*    X     = (float*)   (W + 64 * MB);
    float*    Y     = (float*)   (W + 32 * MB);  // aliases qb/q1/q2 (dead by conv time)
    ushort_t* ybf   = (ushort_t*)(W + 48 * MB);  // aliases k1/k2 (dead by rms time)
    float*    ctab  = (float*)   (W + 80 * MB);
    float*    stab  = (float*)   (W + 80 * MB + 256 * 1024);
    float*    gbuf  = (float*)   (W + 80 * MB + 512 * 1024);
    float*    lam   = (float*)   (W + 80 * MB + 520 * 1024);

    lambda_kernel<<<1, 64, 0, stream>>>(lq1, lk1, lq2, lk2, lam);
    gfilt_kernel<<<129, 256, 0, stream>>>(gbuf);
    rottab<<<256, 256, 0, stream>>>(ctab, stab);
    cvt_bf16<<<2048, 256, 0, stream>>>(query, qb);
    wtrans<<<dim3(32, 32, 4), 256, 0, stream>>>(Wq, Wk, Wv, Wout, WqT, WkT, WvT, WoutT);

    dim3 ggrid(16, 16);
    gemm_bf16<MODE_QK><<<ggrid, 256, 0, stream>>>(qb, WqT, nullptr, q1, q2, ctab, stab);
    gemm_bf16<MODE_QK><<<ggrid, 256, 0, stream>>>(qb, WkT, nullptr, k1, k2, ctab, stab);
    gemm_bf16<MODE_V><<<ggrid, 256, 0, stream>>>(qb, WvT, nullptr, v1T, v2T, nullptr, nullptr);

    dim3 agrid(32, 16);
    attn_mfma<<<agrid, 256, 0, stream>>>(q1, k1, v1T, v2T, X, lam, 0);
    attn_mfma<<<agrid, 256, 0, stream>>>(q2, k2, v1T, v2T, X, lam, 1);

    conv_t<<<dim3(32, 32), 256, 0, stream>>>(X, gbuf, Y);
    rms_bf<<<32768, 64, 0, stream>>>(Y, rmsw, ybf);

    gemm_bf16<MODE_PLAIN><<<ggrid, 256, 0, stream>>>(ybf, WoutT, out, nullptr, nullptr, nullptr, nullptr);
}

// Round 4
// 432.768 us; speedup vs baseline: 8.9712x; 1.0839x over previous
//
#include <hip/hip_runtime.h>
#include <math.h>

#define LAMBDA_INIT_F 0.7836057665316245f
#define ONE_MINUS_LI  0.2163942334683755f

typedef unsigned short ushort_t;
typedef unsigned int   uint32;
typedef unsigned long long u64;
typedef __attribute__((ext_vector_type(8))) short short8;
typedef __attribute__((ext_vector_type(4))) float f32x4;

// float -> bf16 (RNE)
__device__ __forceinline__ ushort_t f2bf(float f) {
    union { float f; uint32 u; } x; x.f = f;
    uint32 r = (x.u + 0x7fffu + ((x.u >> 16) & 1u)) >> 16;
    return (ushort_t)r;
}

// async global->LDS, 16B per lane. lds must be wave-uniform base; HW adds lane*16.
__device__ __forceinline__ void gld16(ushort_t* lds, const ushort_t* g) {
    __builtin_amdgcn_global_load_lds(
        (const __attribute__((address_space(1))) uint32*)g,
        (__attribute__((address_space(3))) uint32*)lds,
        16, 0, 0);
}

// ---------------------------------------------------------------------------
__global__ __launch_bounds__(64) void lambda_kernel(
    const float* __restrict__ lq1, const float* __restrict__ lk1,
    const float* __restrict__ lq2, const float* __restrict__ lk2,
    float* __restrict__ lam)
{
    int l = threadIdx.x;
    float p1 = lq1[l] * lk1[l];
    float p2 = lq2[l] * lk2[l];
    for (int off = 32; off; off >>= 1) {
        p1 += __shfl_down(p1, off);
        p2 += __shfl_down(p2, off);
    }
    if (l == 0) lam[0] = expf(p1) - expf(p2) + LAMBDA_INIT_F;
}

// g[j] = irfft(gaussian filter)[tau=j-64], j in [0,129). Parallel k-sum.
__global__ __launch_bounds__(256) void gfilt_kernel(float* __restrict__ g)
{
    __shared__ float red[4];
    const int j = blockIdx.x;            // 0..128
    int tau = j - 64;
    int ta = tau < 0 ? -tau : tau;       // cos is even
    const int tid = threadIdx.x;
    float acc = 0.0f;
    for (int k = tid; k <= 1024; k += 256) {
        float w = (k == 0 || k == 1024) ? 1.0f : 2.0f;
        float r = (float)k * (1.0f / 153.6f);
        float f = expf(-0.5f * r * r);
        int m = (k * ta) & 2047;
        float ang = (float)m * 3.0679615757712823e-3f;
        acc += w * f * cosf(ang);
    }
    for (int off = 32; off; off >>= 1) acc += __shfl_down(acc, off);
    if ((tid & 63) == 0) red[tid >> 6] = acc;
    __syncthreads();
    if (tid == 0)
        g[j] = (red[0] + red[1] + red[2] + red[3]) * (1.0f / 2048.0f);
}

// rotary tables: ct/st[t*32 + i] = cos/sin(t * 10000^(-i/32))
__global__ __launch_bounds__(256) void rottab(float* __restrict__ ct, float* __restrict__ st)
{
    int id = blockIdx.x * 256 + threadIdx.x;
    int t = id >> 5, i = id & 31;
    double inv = exp(-0.28782313662425575 * (double)i);
    double a = (double)t * inv;
    ct[id] = (float)cos(a);
    st[id] = (float)sin(a);
}

// fp32 -> bf16 elementwise (8/thread)
__global__ __launch_bounds__(256) void cvt_bf16(const float* __restrict__ s, ushort_t* __restrict__ d)
{
    int i = (blockIdx.x * 256 + threadIdx.x) * 8;
    float4 a = *(const float4*)(s + i);
    float4 b = *(const float4*)(s + i + 4);
    uint4 pk;
    pk.x = (uint32)f2bf(a.x) | ((uint32)f2bf(a.y) << 16);
    pk.y = (uint32)f2bf(a.z) | ((uint32)f2bf(a.w) << 16);
    pk.z = (uint32)f2bf(b.x) | ((uint32)f2bf(b.y) << 16);
    pk.w = (uint32)f2bf(b.z) | ((uint32)f2bf(b.w) << 16);
    *(uint4*)(d + i) = pk;
}

// Transpose W[k][n] fp32 -> WT[n'][k] bf16. For z<2 (Wq,Wk) permute n within each
// 64-col head2 group: n' = head2*64 + (d&1)*32 + (d>>1)  (de-interleave rotary pairs)
__global__ __launch_bounds__(256) void wtrans(
    const float* __restrict__ Wq, const float* __restrict__ Wk,
    const float* __restrict__ Wv, const float* __restrict__ Wo,
    ushort_t* __restrict__ Tq, ushort_t* __restrict__ Tk,
    ushort_t* __restrict__ Tv, ushort_t* __restrict__ To)
{
    int z = blockIdx.z;
    const float* S = (z == 0) ? Wq : (z == 1) ? Wk : (z == 2) ? Wv : Wo;
    ushort_t* Dt = (z == 0) ? Tq : (z == 1) ? Tk : (z == 2) ? Tv : To;
    bool perm = (z < 2);
    __shared__ float Ls[64 * 65];
    const int tid = threadIdx.x;
    const int n0 = blockIdx.x * 64, k0 = blockIdx.y * 64;
    #pragma unroll
    for (int it = 0; it < 4; ++it) {
        int kk = it * 16 + (tid >> 4);
        int nn = (tid & 15) * 4;
        float4 v = *(const float4*)(S + (size_t)(k0 + kk) * 2048 + n0 + nn);
        Ls[(nn + 0) * 65 + kk] = v.x;
        Ls[(nn + 1) * 65 + kk] = v.y;
        Ls[(nn + 2) * 65 + kk] = v.z;
        Ls[(nn + 3) * 65 + kk] = v.w;
    }
    __syncthreads();
    int nl = tid >> 2, kc = (tid & 3) * 16;
    int ng = n0 + nl;
    int nd = perm ? ((ng & ~63) | ((ng & 1) << 5) | ((ng & 63) >> 1)) : ng;
    uint4 p0, p1;
    const float* row = Ls + nl * 65 + kc;
    p0.x = (uint32)f2bf(row[0])  | ((uint32)f2bf(row[1])  << 16);
    p0.y = (uint32)f2bf(row[2])  | ((uint32)f2bf(row[3])  << 16);
    p0.z = (uint32)f2bf(row[4])  | ((uint32)f2bf(row[5])  << 16);
    p0.w = (uint32)f2bf(row[6])  | ((uint32)f2bf(row[7])  << 16);
    p1.x = (uint32)f2bf(row[8])  | ((uint32)f2bf(row[9])  << 16);
    p1.y = (uint32)f2bf(row[10]) | ((uint32)f2bf(row[11]) << 16);
    p1.z = (uint32)f2bf(row[12]) | ((uint32)f2bf(row[13]) << 16);
    p1.w = (uint32)f2bf(row[14]) | ((uint32)f2bf(row[15]) << 16);
    *(uint4*)(Dt + (size_t)nd * 2048 + k0 + kc) = p0;
    *(uint4*)(Dt + (size_t)nd * 2048 + k0 + kc + 8) = p1;
}

// ---------------------------------------------------------------------------
// Fused QKV GEMM: C = qb(2048x2048) * WT^T where WT = [WqT;WkT;WvT] (6144x2048).
// Epilogue by n-region: 0 -> rotary -> q1/q2, 1 -> rotary -> k1/k2, 2 -> V^T.
__global__ __launch_bounds__(256) void gemm_qkv(
    const ushort_t* __restrict__ A, const ushort_t* __restrict__ WT,
    ushort_t* __restrict__ q1, ushort_t* __restrict__ q2,
    ushort_t* __restrict__ k1, ushort_t* __restrict__ k2,
    ushort_t* __restrict__ v1T, ushort_t* __restrict__ v2T,
    const float* __restrict__ ctab, const float* __restrict__ stab)
{
    __shared__ ushort_t As[8192];
    __shared__ ushort_t Bs[8192];
    const int tid = threadIdx.x;
    const int w = tid >> 6, lane = tid & 63;
    const int quad = lane >> 4, l15 = lane & 15;
    const int wr = w >> 1, wc = w & 1;
    const int rb = blockIdx.y * 128, cb = blockIdx.x * 128;

    f32x4 acc[4][4];
    #pragma unroll
    for (int i = 0; i < 4; ++i)
        #pragma unroll
        for (int j = 0; j < 4; ++j) acc[i][j] = (f32x4)0.0f;

    for (int k0 = 0; k0 < 2048; k0 += 64) {
        #pragma unroll
        for (int u = 0; u < 4; ++u) {
            int off = (w * 4 + u) * 512;
            int Lc = (off >> 3) + lane;
            int row = Lc >> 3, cc = (Lc & 7) ^ (row & 7);
            gld16(As + off, A + (size_t)(rb + row) * 2048 + k0 + cc * 8);
            gld16(Bs + off, WT + (size_t)(cb + row) * 2048 + k0 + cc * 8);
        }
        __syncthreads();
        #pragma unroll
        for (int ks = 0; ks < 2; ++ks) {
            short8 af[4], bfr[4];
            #pragma unroll
            for (int mi = 0; mi < 4; ++mi) {
                int r = wr * 64 + mi * 16 + l15;
                af[mi] = *(const short8*)(As + r * 64 + ((ks * 4 + quad) ^ (r & 7)) * 8);
            }
            #pragma unroll
            for (int nj = 0; nj < 4; ++nj) {
                int r = wc * 64 + nj * 16 + l15;
                bfr[nj] = *(const short8*)(Bs + r * 64 + ((ks * 4 + quad) ^ (r & 7)) * 8);
            }
            #pragma unroll
            for (int mi = 0; mi < 4; ++mi)
                #pragma unroll
                for (int nj = 0; nj < 4; ++nj)
                    acc[mi][nj] = __builtin_amdgcn_mfma_f32_16x16x32_bf16(
                        af[mi], bfr[nj], acc[mi][nj], 0, 0, 0);
        }
        __syncthreads();
    }

    const int region = cb >> 11;         // 0=Q, 1=K, 2=V
    const int nloc = cb & 2047;
    if (region < 2) {
        int head2 = (nloc + wc * 64) >> 6;
        ushort_t* b1 = region ? k1 : q1;
        ushort_t* b2 = region ? k2 : q2;
        ushort_t* dst = ((head2 & 1) ? b2 : b1) + (size_t)(head2 >> 1) * 2048 * 64;
        #pragma unroll
        for (int mi = 0; mi < 4; ++mi)
            #pragma unroll
            for (int r = 0; r < 4; ++r) {
                int t = rb + wr * 64 + mi * 16 + quad * 4 + r;
                const float* ctr = ctab + t * 32;
                const float* str = stab + t * 32;
                #pragma unroll
                for (int nj = 0; nj < 2; ++nj) {
                    int i = nj * 16 + l15;
                    float c = ctr[i], s = str[i];
                    float x1 = acc[mi][nj][r], x2 = acc[mi][nj + 2][r];
                    dst[(size_t)t * 64 + i]      = f2bf(x1 * c - x2 * s);
                    dst[(size_t)t * 64 + 32 + i] = f2bf(x1 * s + x2 * c);
                }
            }
    } else {
        #pragma unroll
        for (int mi = 0; mi < 4; ++mi)
            #pragma unroll
            for (int nj = 0; nj < 4; ++nj) {
                int cg = nloc + wc * 64 + nj * 16 + l15;
                int hh = cg >> 7, pr = (cg >> 6) & 1, d = cg & 63;
                int tb = rb + wr * 64 + mi * 16 + quad * 4;
                ushort_t* dst = (pr ? v2T : v1T) + ((size_t)(hh * 64 + d)) * 2048 + tb;
                u64 pk = (u64)f2bf(acc[mi][nj][0])
                       | ((u64)f2bf(acc[mi][nj][1]) << 16)
                       | ((u64)f2bf(acc[mi][nj][2]) << 32)
                       | ((u64)f2bf(acc[mi][nj][3]) << 48);
                *(u64*)dst = pk;
            }
    }
}

// ---------------------------------------------------------------------------
// Merged double-attention with double-buffered K/V staging.
// Per (qt,h) block: stages K1,K2,V1,V2 tiles (dbuf, prefetch kt+1 during kt),
// computes both flash attentions, writes X = o1 - lam*o2 (fp32).
#define PSTRIDE 88

__device__ __forceinline__ void attn_step(
    const ushort_t* __restrict__ Kb, const ushort_t* __restrict__ V1b,
    const ushort_t* __restrict__ V2b, ushort_t* __restrict__ pw,
    const short8* qb, f32x4* O, float& m_i, float& l_i,
    int quad, int l15, int row_l, bool diag)
{
    f32x4 s[4];
    #pragma unroll
    for (int j = 0; j < 4; ++j) s[j] = (f32x4)0.0f;
    #pragma unroll
    for (int ks = 0; ks < 2; ++ks)
        #pragma unroll
        for (int j = 0; j < 4; ++j) {
            int r = j * 16 + l15;
            short8 kf = *(const short8*)(Kb + r * 64 + ((ks * 4 + quad) ^ (r & 7)) * 8);
            s[j] = __builtin_amdgcn_mfma_f32_16x16x32_bf16(kf, qb[ks], s[j], 0, 0, 0);
        }
    float pv[16];
    float mx = -1e30f;
    #pragma unroll
    for (int j = 0; j < 4; ++j)
        #pragma unroll
        for (int r = 0; r < 4; ++r) {
            float v = s[j][r] * 0.125f;
            if (diag) {
                int kp = j * 16 + quad * 4 + r;
                v = (kp <= row_l) ? v : -1e30f;
            }
            pv[j * 4 + r] = v;
            mx = fmaxf(mx, v);
        }
    mx = fmaxf(mx, __shfl_xor(mx, 16));
    mx = fmaxf(mx, __shfl_xor(mx, 32));
    float newm = fmaxf(m_i, mx);
    float alpha = __expf(m_i - newm);
    float sum = 0.0f;
    ushort_t pb[16];
    #pragma unroll
    for (int i = 0; i < 16; ++i) {
        float p = __expf(pv[i] - newm);
        sum += p;
        pb[i] = f2bf(p);
    }
    sum += __shfl_xor(sum, 16);
    sum += __shfl_xor(sum, 32);
    l_i = l_i * alpha + sum;
    m_i = newm;
    #pragma unroll
    for (int j = 0; j < 4; ++j) {
        u64 pk = (u64)pb[j * 4] | ((u64)pb[j * 4 + 1] << 16)
               | ((u64)pb[j * 4 + 2] << 32) | ((u64)pb[j * 4 + 3] << 48);
        *(u64*)(pw + l15 * PSTRIDE + j * 16 + quad * 4) = pk;
    }
    float av0 = __shfl(alpha, quad * 4 + 0);
    float av1 = __shfl(alpha, quad * 4 + 1);
    float av2 = __shfl(alpha, quad * 4 + 2);
    float av3 = __shfl(alpha, quad * 4 + 3);
    #pragma unroll
    for (int nt = 0; nt < 8; ++nt) {
        O[nt][0] *= av0; O[nt][1] *= av1; O[nt][2] *= av2; O[nt][3] *= av3;
    }
    #pragma unroll
    for (int ks = 0; ks < 2; ++ks) {
        short8 pf = *(const short8*)(pw + l15 * PSTRIDE + ks * 32 + quad * 8);
        #pragma unroll
        for (int nt = 0; nt < 8; ++nt) {
            const ushort_t* Vs = (nt < 4) ? V1b : V2b;
            int d = (nt & 3) * 16 + l15;
            short8 vf = *(const short8*)(Vs + d * 64 + ((ks * 4 + quad) ^ (d & 7)) * 8);
            O[nt] = __builtin_amdgcn_mfma_f32_16x16x32_bf16(pf, vf, O[nt], 0, 0, 0);
        }
    }
}

__global__ __launch_bounds__(256) void attn_merged(
    const ushort_t* __restrict__ q1, const ushort_t* __restrict__ k1,
    const ushort_t* __restrict__ q2, const ushort_t* __restrict__ k2,
    const ushort_t* __restrict__ v1T, const ushort_t* __restrict__ v2T,
    float* __restrict__ X, const float* __restrict__ lam_ptr)
{
    __shared__ ushort_t KV[2][16384];   // per buf: K1 @0, K2 @4096, V1 @8192, V2 @12288
    __shared__ ushort_t Ps[4][16 * PSTRIDE];

    const int tid = threadIdx.x;
    const int w = tid >> 6, lane = tid & 63;
    const int quad = lane >> 4, l15 = lane & 15;
    const int h = blockIdx.y;
    const int qt = 31 - blockIdx.x;     // heavy blocks first
    const float lam = lam_ptr[0];

    const ushort_t* k1h = k1 + (size_t)h * 2048 * 64;
    const ushort_t* k2h = k2 + (size_t)h * 2048 * 64;
    const ushort_t* v1h = v1T + (size_t)h * 64 * 2048;
    const ushort_t* v2h = v2T + (size_t)h * 64 * 2048;

    // stage Q1/Q2 tiles into buf0 temporarily, read fragments to regs
    {
        const ushort_t* q1t = q1 + ((size_t)h * 2048 + qt * 64) * 64;
        const ushort_t* q2t = q2 + ((size_t)h * 2048 + qt * 64) * 64;
        #pragma unroll
        for (int u = 0; u < 2; ++u) {
            int off = (w * 2 + u) * 512;
            int Lc = (off >> 3) + lane;
            int row = Lc >> 3, cc = (Lc & 7) ^ (row & 7);
            gld16(&KV[0][0] + off, q1t + row * 64 + cc * 8);
            gld16(&KV[0][4096] + off, q2t + row * 64 + cc * 8);
        }
    }
    __syncthreads();
    short8 qb1[2], qb2[2];
    {
        int r = w * 16 + l15;
        #pragma unroll
        for (int ks = 0; ks < 2; ++ks) {
            int sw = ((ks * 4 + quad) ^ (r & 7)) * 8;
            qb1[ks] = *(const short8*)(&KV[0][0] + r * 64 + sw);
            qb2[ks] = *(const short8*)(&KV[0][4096] + r * 64 + sw);
        }
    }
    __syncthreads();

    // stage kt=0 into buf0
    {
        #pragma unroll
        for (int u = 0; u < 2; ++u) {
            int off = (w * 2 + u) * 512;
            int Lc = (off >> 3) + lane;
            int row = Lc >> 3, cc = (Lc & 7) ^ (row & 7);
            gld16(&KV[0][0] + off,     k1h + row * 64 + cc * 8);
            gld16(&KV[0][4096] + off,  k2h + row * 64 + cc * 8);
            gld16(&KV[0][8192] + off,  v1h + row * 2048 + cc * 8);
            gld16(&KV[0][12288] + off, v2h + row * 2048 + cc * 8);
        }
    }
    __syncthreads();

    f32x4 O1[8], O2[8];
    #pragma unroll
    for (int i = 0; i < 8; ++i) { O1[i] = (f32x4)0.0f; O2[i] = (f32x4)0.0f; }
    float m1 = -1e30f, l1 = 0.0f, m2 = -1e30f, l2 = 0.0f;
    const int row_l = w * 16 + l15;

    for (int kt = 0; kt <= qt; ++kt) {
        const int cur = kt & 1;
        if (kt < qt) {
            // prefetch kt+1 into the other buffer (overlaps with compute below)
            int kn = kt + 1;
            ushort_t* nb = &KV[cur ^ 1][0];
            #pragma unroll
            for (int u = 0; u < 2; ++u) {
                int off = (w * 2 + u) * 512;
                int Lc = (off >> 3) + lane;
                int row = Lc >> 3, cc = (Lc & 7) ^ (row & 7);
                gld16(nb + off,         k1h + (kn * 64 + row) * 64 + cc * 8);
                gld16(nb + 4096 + off,  k2h + (kn * 64 + row) * 64 + cc * 8);
                gld16(nb + 8192 + off,  v1h + row * 2048 + kn * 64 + cc * 8);
                gld16(nb + 12288 + off, v2h + row * 2048 + kn * 64 + cc * 8);
            }
        }
        const ushort_t* cb = &KV[cur][0];
        bool diag = (kt == qt);
        attn_step(cb, cb + 8192, cb + 12288, Ps[w], qb1, O1, m1, l1, quad, l15, row_l, diag);
        attn_step(cb + 4096, cb + 8192, cb + 12288, Ps[w], qb2, O2, m2, l2, quad, l15, row_l, diag);
        __syncthreads();
    }

    // epilogue: X = o1/l1 - lam * o2/l2
    float r10 = 1.0f / __shfl(l1, quad * 4 + 0);
    float r11 = 1.0f / __shfl(l1, quad * 4 + 1);
    float r12 = 1.0f / __shfl(l1, quad * 4 + 2);
    float r13 = 1.0f / __shfl(l1, quad * 4 + 3);
    float r20 = lam / __shfl(l2, quad * 4 + 0);
    float r21 = lam / __shfl(l2, quad * 4 + 1);
    float r22 = lam / __shfl(l2, quad * 4 + 2);
    float r23 = lam / __shfl(l2, quad * 4 + 3);
    int tb = qt * 64 + w * 16 + quad * 4;
    #pragma unroll
    for (int nt = 0; nt < 8; ++nt) {
        int col = h * 128 + nt * 16 + l15;
        X[(size_t)(tb + 0) * 2048 + col] = O1[nt][0] * r10 - O2[nt][0] * r20;
        X[(size_t)(tb + 1) * 2048 + col] = O1[nt][1] * r11 - O2[nt][1] * r21;
        X[(size_t)(tb + 2) * 2048 + col] = O1[nt][2] * r12 - O2[nt][2] * r22;
        X[(size_t)(tb + 3) * 2048 + col] = O1[nt][3] * r13 - O2[nt][3] * r23;
    }
}

// ---------------------------------------------------------------------------
// LDS-tiled truncated circular conv along t (129 taps); g[j]=g(tau=j-64)
__global__ __launch_bounds__(256) void conv_t(
    const float* __restrict__ X, const float* __restrict__ g, float* __restrict__ Y)
{
    __shared__ float Xs[192 * 64];
    __shared__ float gs[129];
    const int tid = threadIdx.x;
    const int c0 = blockIdx.x * 64, t0 = blockIdx.y * 64;
    const int c = tid & 63, tg = tid >> 6;
    for (int j = tg; j < 192; j += 4)
        Xs[j * 64 + c] = X[(size_t)((t0 - 64 + j) & 2047) * 2048 + c0 + c];
    if (tid < 129) gs[tid] = g[tid];
    __syncthreads();
    float accv[16];
    #pragma unroll
    for (int i = 0; i < 16; ++i) accv[i] = 0.0f;
    const int tl0 = tg * 16;
    for (int tap = 0; tap < 129; ++tap) {
        float gv = gs[tap];
        int base = (tl0 + 128 - tap) * 64 + c;
        #pragma unroll
        for (int i = 0; i < 16; ++i) accv[i] += gv * Xs[base + i * 64];
    }
    #pragma unroll
    for (int i = 0; i < 16; ++i)
        Y[(size_t)(t0 + tl0 + i) * 2048 + c0 + c] = accv[i];
}

// RMSNorm over 128 per (t,h); writes bf16 for the final GEMM
__global__ __launch_bounds__(64) void rms_bf(
    const float* __restrict__ Y, const float* __restrict__ wgt, ushort_t* __restrict__ yb)
{
    int grp = blockIdx.x;
    int t = grp >> 4, hh = grp & 15, l = threadIdx.x;
    size_t base = (size_t)t * 2048 + hh * 128;
    float a = Y[base + l];
    float b = Y[base + 64 + l];
    float ss = a * a + b * b;
    for (int off = 32; off; off >>= 1) ss += __shfl_down(ss, off);
    ss = __shfl(ss, 0);
    float r = rsqrtf(ss * (1.0f / 128.0f) + 1e-5f) * ONE_MINUS_LI;
    yb[base + l]      = f2bf(a * r * wgt[l]);
    yb[base + 64 + l] = f2bf(b * r * wgt[64 + l]);
}

// ---------------------------------------------------------------------------
// Final GEMM: 64x128 tile (grid 512 -> 2 blocks/CU). out = ybf * WoutT^T, fp32 out.
__global__ __launch_bounds__(256) void gemm_out(
    const ushort_t* __restrict__ A, const ushort_t* __restrict__ BT,
    float* __restrict__ C)
{
    __shared__ ushort_t As[4096];
    __shared__ ushort_t Bs[8192];
    const int tid = threadIdx.x;
    const int w = tid >> 6, lane = tid & 63;
    const int quad = lane >> 4, l15 = lane & 15;
    const int wr = w >> 1, wc = w & 1;
    const int rb = blockIdx.y * 64, cb = blockIdx.x * 128;

    f32x4 acc[2][4];
    #pragma unroll
    for (int i = 0; i < 2; ++i)
        #pragma unroll
        for (int j = 0; j < 4; ++j) acc[i][j] = (f32x4)0.0f;

    for (int k0 = 0; k0 < 2048; k0 += 64) {
        #pragma unroll
        for (int u = 0; u < 2; ++u) {
            int off = (w * 2 + u) * 512;
            int Lc = (off >> 3) + lane;
            int row = Lc >> 3, cc = (Lc & 7) ^ (row & 7);
            gld16(As + off, A + (size_t)(rb + row) * 2048 + k0 + cc * 8);
        }
        #pragma unroll
        for (int u = 0; u < 4; ++u) {
            int off = (w * 4 + u) * 512;
            int Lc = (off >> 3) + lane;
            int row = Lc >> 3, cc = (Lc & 7) ^ (row & 7);
            gld16(Bs + off, BT + (size_t)(cb + row) * 2048 + k0 + cc * 8);
        }
        __syncthreads();
        #pragma unroll
        for (int ks = 0; ks < 2; ++ks) {
            short8 af[2], bfr[4];
            #pragma unroll
            for (int mi = 0; mi < 2; ++mi) {
                int r = wr * 32 + mi * 16 + l15;
                af[mi] = *(const short8*)(As + r * 64 + ((ks * 4 + quad) ^ (r & 7)) * 8);
            }
            #pragma unroll
            for (int nj = 0; nj < 4; ++nj) {
                int r = wc * 64 + nj * 16 + l15;
                bfr[nj] = *(const short8*)(Bs + r * 64 + ((ks * 4 + quad) ^ (r & 7)) * 8);
            }
            #pragma unroll
            for (int mi = 0; mi < 2; ++mi)
                #pragma unroll
                for (int nj = 0; nj < 4; ++nj)
                    acc[mi][nj] = __builtin_amdgcn_mfma_f32_16x16x32_bf16(
                        af[mi], bfr[nj], acc[mi][nj], 0, 0, 0);
        }
        __syncthreads();
    }

    #pragma unroll
    for (int mi = 0; mi < 2; ++mi)
        #pragma unroll
        for (int nj = 0; nj < 4; ++nj) {
            int cg = cb + wc * 64 + nj * 16 + l15;
            #pragma unroll
            for (int r = 0; r < 4; ++r) {
                int t = rb + wr * 32 + mi * 16 + quad * 4 + r;
                C[(size_t)t * 2048 + cg] = acc[mi][nj][r];
            }
        }
}

// ---------------------------------------------------------------------------
extern "C" void kernel_launch(void* const* d_in, const int* in_sizes, int n_in,
                              void* d_out, int out_size, void* d_ws, size_t ws_size,
                              hipStream_t stream)
{
    const float* query = (const float*)d_in[0];
    const float* Wq    = (const float*)d_in[1];
    const float* Wk    = (const float*)d_in[2];
    const float* Wv    = (const float*)d_in[3];
    const float* Wout  = (const float*)d_in[4];
    const float* lq1   = (const float*)d_in[5];
    const float* lk1   = (const float*)d_in[6];
    const float* lq2   = (const float*)d_in[7];
    const float* lk2   = (const float*)d_in[8];
    const float* rmsw  = (const float*)d_in[9];
    float* out = (float*)d_out;

    const size_t MB = 1ull << 20;
    char* W = (char*)d_ws;
    ushort_t* WqT   = (ushort_t*)(W + 0 * MB);   // WqT/WkT/WvT contiguous: 24MB block
    ushort_t* WkT   = (ushort_t*)(W + 8 * MB);
    ushort_t* WvT   = (ushort_t*)(W + 16 * MB);
    ushort_t* WoutT = (ushort_t*)(W + 24 * MB);
    ushort_t* qb    = (ushort_t*)(W + 32 * MB);
    ushort_t* q1    = (ushort_t*)(W + 40 * MB);
    ushort_t* q2    = (ushort_t*)(W + 44 * MB);
    ushort_t* k1    = (ushort_t*)(W + 48 * MB);
    ushort_t* k2    = (ushort_t*)(W + 52 * MB);
    ushort_t* v1T   = (ushort_t*)(W + 56 * MB);
    ushort_t* v2T   = (ushort_t*)(W + 60 * MB);
    float*    X     = (float*)   (W + 64 * MB);
    float*    Y     = (float*)   (W + 32 * MB);  // aliases qb/q1/q2 (dead by conv time)
    ushort_t* ybf   = (ushort_t*)(W + 48 * MB);  // aliases k1/k2 (dead by rms time)
    float*    ctab  = (float*)   (W + 80 * MB);
    float*    stab  = (float*)   (W + 80 * MB + 256 * 1024);
    float*    gbuf  = (float*)   (W + 80 * MB + 512 * 1024);
    float*    lam   = (float*)   (W + 80 * MB + 520 * 1024);

    lambda_kernel<<<1, 64, 0, stream>>>(lq1, lk1, lq2, lk2, lam);
    gfilt_kernel<<<129, 256, 0, stream>>>(gbuf);
    rottab<<<256, 256, 0, stream>>>(ctab, stab);
    cvt_bf16<<<2048, 256, 0, stream>>>(query, qb);
    wtrans<<<dim3(32, 32, 4), 256, 0, stream>>>(Wq, Wk, Wv, Wout, WqT, WkT, WvT, WoutT);

    gemm_qkv<<<dim3(48, 16), 256, 0, stream>>>(qb, WqT, q1, q2, k1, k2, v1T, v2T, ctab, stab);

    attn_merged<<<dim3(32, 16), 256, 0, stream>>>(q1, k1, q2, k2, v1T, v2T, X, lam);

    conv_t<<<dim3(32, 32), 256, 0, stream>>>(X, gbuf, Y);
    rms_bf<<<32768, 64, 0, stream>>>(Y, rmsw, ybf);

    gemm_out<<<dim3(16, 32), 256, 0, stream>>>(ybf, WoutT, out);
}